// Round 3
// baseline (433.001 us; speedup 1.0000x reference)
//
#include <hip/hip_runtime.h>
#include <cstdint>

#define C_ 256
#define H_ 96
#define W_ 160
#define HW_ (H_*W_)
#define TH 16
#define TW 16
#define PP 4
#define NW 9                 // waves per block, wave id == dy
#define NTHR 576
#define CCH 8                // channels per chunk
#define NCH 32               // C_/CCH
#define S2STR 28             // d2 row stride (words) = 6 data f4 + 1 pad f4
#define S2CH 672             // 24*28 words per channel (d2)
#define BUFW (CCH*S2CH)      // 5376 words per buffer (21,504 B)
#define F4PCH 168            // f4 per channel incl pads: 24*7
#define NF4 1344             // f4 per chunk = CCH*168 = exactly 21 wave-slots
#define NSLOT 3              // slots per wave (9*3=27 >= 21; extras masked)
#define CHSTRIDE (CCH*HW_)   // floats advanced per chunk

// Async global->LDS, 16B per lane. LDS dest = wave-uniform base + lane*16.
__device__ __forceinline__ void async_ld16(const float* g, float* l) {
  __builtin_amdgcn_global_load_lds(
      (const __attribute__((address_space(1))) void*)g,
      (__attribute__((address_space(3))) void*)l, 16, 0, 0);
}

// R3 structure: d2-only in LDS (A loaded per-thread from global, L1-resident
// 8KB/chunk tile read by all 9 waves). LDS reads per chunk-block drop 25%
// (288->216 b128) and staging drops 31->21 slots. Double-buffer = 43,008 B
// so 2 blocks/CU = 86KB -- under the suspected ~128KB workgroup-packing LDS
// budget that blocked co-residency at R2's 2x63,488=126,976.
// Register watchdog: acc 36 + B window 12 + A 8 + ptrs/addr ~20 -> ~76 < 84
// empirical budget (spill telltale = WRITE_SIZE >> 39 MB).
__global__
__attribute__((amdgpu_flat_work_group_size(NTHR, NTHR)))
void corr_kernel(
    const float* __restrict__ d1, const float* __restrict__ d2,
    float* __restrict__ out)
{
  __shared__ float sm[2*BUFW];   // 43,008 B
  const int tid  = threadIdx.x;
  const int lane = tid & 63;
  const int w    = tid >> 6;     // wave id == dy (0..8)
  const int n  = blockIdx.z;
  const int y0 = blockIdx.y * TH;
  const int x0 = blockIdx.x * TW;

  // ---- staging precompute: linear f4 index F -> LDS word 4F (pads incl.)
  //   F = c*168 + ry*7 + j ; 4F = c*672 + 28*ry + 4j == compute-side layout.
  const float* gp[NSLOT];
  unsigned vmask = 0;
  #pragma unroll
  for (int s = 0; s < NSLOT; ++s) {
    const int m = s*NW + w;              // wave-uniform slot id
    const int F = m*64 + lane;
    const float* p = d2;
    bool v = false;
    if (F < NF4) {
      const int c   = F / F4PCH;
      const int rem = F % F4PCH;
      const int ry = rem / 7, j = rem % 7;   // 24 rows x 7 f4 (j==6 pad)
      const int gy = y0 - 4 + ry, gx = x0 - 4 + 4*j;
      v = (j < 6) & (gy >= 0) & (gy < H_) & (gx >= 0) & (gx < W_);
      p = d2 + (((n*C_ + c)*H_ + gy)*W_ + gx);
    }
    gp[s] = p;
    vmask |= (unsigned)v << s;
  }

  // ---- zero LDS once: OOB-halo + pad slots are never staged over, so they
  // stay zero for all chunks (same exec mask every chunk).
  {
    const float4 z = make_float4(0.f, 0.f, 0.f, 0.f);
    float4* s4 = (float4*)sm;
    #pragma unroll
    for (int i = 0; i < 5; ++i) {
      const int idx = tid + i*NTHR;
      if (idx < (2*BUFW)/4) s4[idx] = z;
    }
  }
  __syncthreads();

  float acc[9][PP];
  #pragma unroll
  for (int dx = 0; dx < 9; ++dx)
    #pragma unroll
    for (int p = 0; p < PP; ++p) acc[dx][p] = 0.f;

  // Lane map: r fastest (conflict-behavior equivalent across odd strides;
  // kept from R2). Thread (r,q) computes out rows y0+r, cols x0+4q..+3.
  const int r  = lane & 15;
  const int q  = lane >> 4;            // x-group 0..3
  const int l2 = (r + w)*S2STR + q*PP; // within-channel d2 word offset

  // Per-thread A pointer (global, L1-served: same 8KB tile read by 9 waves).
  const float* pA = d1 + ((size_t)n*C_*HW_ + (y0 + r)*W_ + x0 + q*PP);

  auto stage = [&](int k, int b) {
    const size_t koff = (size_t)k * CHSTRIDE;
    float* dst0 = sm + b*BUFW;
    #pragma unroll
    for (int s = 0; s < NSLOT; ++s)
      if (vmask & (1u << s))
        async_ld16(gp[s] + koff, dst0 + (s*NW + w)*256);
  };

  auto compute = [&](int k, int b) {
    const float* base = sm + b*BUFW;
    const float* pAk  = pA + (size_t)k * CHSTRIDE;
    #pragma unroll
    for (int c = 0; c < CCH; ++c) {
      float4 A = *(const float4*)(pAk + c*HW_);
      const float* p2 = base + c*S2CH + l2;
      float4 B0 = *(const float4*)(p2);
      float4 B1 = *(const float4*)(p2 + 4);
      float4 B2 = *(const float4*)(p2 + 8);
      float a1[4]  = {A.x, A.y, A.z, A.w};
      float a2[12] = {B0.x,B0.y,B0.z,B0.w,B1.x,B1.y,B1.z,B1.w,
                      B2.x,B2.y,B2.z,B2.w};
      #pragma unroll
      for (int dx = 0; dx < 9; ++dx)
        #pragma unroll
        for (int p = 0; p < PP; ++p)
          acc[dx][p] = fmaf(a1[p], a2[p+dx], acc[dx][p]);
    }
  };

  // ---- pipelined main loop: one barrier per chunk; d2 loads for k+1 fly
  // during compute(k) (a full compute phase >> HBM latency, so the
  // __syncthreads vmcnt drain is cheap -- verified R2 analysis).
  stage(0, 0);
  __syncthreads();
  #pragma unroll 1
  for (int k = 0; k < NCH-1; ++k) {
    stage(k+1, (k+1)&1);
    compute(k, k&1);
    __syncthreads();
  }
  compute(NCH-1, (NCH-1)&1);

  // ---- epilogue ----
  const float scale = 1.0f/256.0f;
  const int y  = y0 + r;
  const int xb = x0 + q*PP;
  #pragma unroll
  for (int dx = 0; dx < 9; ++dx) {
    const int qc = w*9 + dx;
    const size_t o = (((size_t)n*81 + qc)*H_ + y)*W_ + xb;
    *(float4*)(out + o) = make_float4(acc[dx][0]*scale, acc[dx][1]*scale,
                                      acc[dx][2]*scale, acc[dx][3]*scale);
  }
}

extern "C" void kernel_launch(void* const* d_in, const int* in_sizes, int n_in,
                              void* d_out, int out_size, void* d_ws, size_t ws_size,
                              hipStream_t stream) {
  const float* d1 = (const float*)d_in[0];
  const float* d2 = (const float*)d_in[1];
  float* out = (float*)d_out;
  dim3 grid(W_/TW, H_/TH, 8);  // 10 x 6 x 8 = 480 blocks
  corr_kernel<<<grid, NTHR, 0, stream>>>(d1, d2, out);
}